// Round 1
// baseline (110.352 us; speedup 1.0000x reference)
//
#include <hip/hip_runtime.h>

// Problem constants (from reference): x [8192, 2048] f32, W [2048, 2048] f32,
// b [2048] f32, out [8192] f32.  out[r] = SCALE * (dot(x[r,:], colsum(W)) + sum(b))
#define DIM   2048
#define NROW  8192
#define SCALE 0.1f

// ws layout (floats): ws[0..DIM-1] = wcol accumulators, ws[DIM] = bsum.

// --- Kernel 1: zero wcol accumulators + reduce b into bsum (single block) ---
__global__ __launch_bounds__(256) void init_kernel(const float* __restrict__ b,
                                                   float* __restrict__ ws) {
    const int t = threadIdx.x;
    // zero wcol (DIM floats) + the bsum slot
    for (int i = t; i < DIM; i += 256) ws[i] = 0.0f;

    // each thread sums 8 elements of b
    float s = 0.0f;
#pragma unroll
    for (int k = 0; k < DIM / 256; ++k) s += b[k * 256 + t];

    // wave64 shuffle reduce
#pragma unroll
    for (int off = 32; off > 0; off >>= 1) s += __shfl_down(s, off, 64);

    __shared__ float part[4];
    const int lane = t & 63, wave = t >> 6;
    if (lane == 0) part[wave] = s;
    __syncthreads();
    if (t == 0) ws[DIM] = part[0] + part[1] + part[2] + part[3];
}

// --- Kernel 2: column sums of W (sum over rows / "out" dim) ---
// grid = (DIM/1024, 64); each block: 256 threads x float4 => 1024 cols, 32 rows.
#define ROWS_PER_BLK 32
__global__ __launch_bounds__(256) void colsum_kernel(const float* __restrict__ W,
                                                     float* __restrict__ ws) {
    const int col4 = blockIdx.x * 256 + threadIdx.x;   // float4 column index
    const int row0 = blockIdx.y * ROWS_PER_BLK;
    const float4* __restrict__ W4 = (const float4*)W;  // [row][DIM/4]

    float ax = 0.f, ay = 0.f, az = 0.f, aw = 0.f;
#pragma unroll 8
    for (int r = 0; r < ROWS_PER_BLK; ++r) {
        float4 v = W4[(size_t)(row0 + r) * (DIM / 4) + col4];
        ax += v.x; ay += v.y; az += v.z; aw += v.w;
    }
    float* dst = ws + col4 * 4;
    atomicAdd(dst + 0, ax);
    atomicAdd(dst + 1, ay);
    atomicAdd(dst + 2, az);
    atomicAdd(dst + 3, aw);
}

// --- Kernel 3: per-row dot(x[r], wcol) + bsum, scaled ---
// one block per row; 256 threads; DIM/4/256 = 2 float4 pairs per thread.
__global__ __launch_bounds__(256) void rowdot_kernel(const float* __restrict__ x,
                                                     const float* __restrict__ ws,
                                                     float* __restrict__ out) {
    const int row = blockIdx.x;
    const int t = threadIdx.x;
    const float4* __restrict__ xr = (const float4*)(x + (size_t)row * DIM);
    const float4* __restrict__ wc = (const float4*)ws;

    float s = 0.0f;
#pragma unroll
    for (int k = 0; k < DIM / 4 / 256; ++k) {   // 2 iterations
        float4 xv = xr[k * 256 + t];
        float4 wv = wc[k * 256 + t];
        s += xv.x * wv.x + xv.y * wv.y + xv.z * wv.z + xv.w * wv.w;
    }

#pragma unroll
    for (int off = 32; off > 0; off >>= 1) s += __shfl_down(s, off, 64);

    __shared__ float part[4];
    const int lane = t & 63, wave = t >> 6;
    if (lane == 0) part[wave] = s;
    __syncthreads();
    if (t == 0) {
        float tot = part[0] + part[1] + part[2] + part[3];
        out[row] = SCALE * (tot + ws[DIM]);
    }
}

extern "C" void kernel_launch(void* const* d_in, const int* in_sizes, int n_in,
                              void* d_out, int out_size, void* d_ws, size_t ws_size,
                              hipStream_t stream) {
    const float* x = (const float*)d_in[0];  // [8192, 2048]
    const float* W = (const float*)d_in[1];  // [2048, 2048]
    const float* b = (const float*)d_in[2];  // [2048]
    float* out = (float*)d_out;              // [8192]
    float* ws  = (float*)d_ws;               // >= (DIM+1)*4 bytes

    init_kernel<<<1, 256, 0, stream>>>(b, ws);

    dim3 cgrid(DIM / 1024, DIM / ROWS_PER_BLK);  // (2, 64) = 128 blocks
    colsum_kernel<<<cgrid, 256, 0, stream>>>(W, ws);

    rowdot_kernel<<<NROW, 256, 0, stream>>>(x, ws, out);
}